// Round 3
// baseline (1422.032 us; speedup 1.0000x reference)
//
#include <hip/hip_runtime.h>
#include <math.h>

#define NN 50000
#define NE 640000
#define DIM 128
#define NH 8

__device__ __forceinline__ float wave_sum64(float v) {
  #pragma unroll
  for (int m = 32; m >= 1; m >>= 1) v += __shfl_xor(v, m, 64);
  return v;
}

// pack two f32 into bf16x2 (RNE); unpack helpers
__device__ __forceinline__ unsigned bf16pk(float a, float b) {
  unsigned ua = __float_as_uint(a); ua = (ua + 0x7fffu + ((ua >> 16) & 1u)) >> 16;
  unsigned ub = __float_as_uint(b); ub = (ub + 0x7fffu + ((ub >> 16) & 1u)) & 0xffff0000u;
  return ua | ub;
}
__device__ __forceinline__ float bf_lo(unsigned v) { return __uint_as_float(v << 16); }
__device__ __forceinline__ float bf_hi(unsigned v) { return __uint_as_float(v & 0xffff0000u); }

// ---------------------------------------------------------------------------
// CSR build
// ---------------------------------------------------------------------------
__global__ __launch_bounds__(256) void csr_count_k(const int* __restrict__ dst,
                                                   int* __restrict__ deg) {
  int e = blockIdx.x * 256 + threadIdx.x;
  if (e < NE) atomicAdd(&deg[dst[e]], 1);
}

#define SCAN_T 1024
#define SCHUNK 49
__global__ __launch_bounds__(1024) void scan_k(const int* __restrict__ deg,
                                               int* __restrict__ off,
                                               int* __restrict__ cursor) {
  __shared__ int part[SCAN_T];
  int t = threadIdx.x;
  int lo = t * SCHUNK, hi = lo + SCHUNK; if (hi > NN) hi = NN;
  int s = 0;
  for (int i = lo; i < hi; ++i) s += deg[i];
  part[t] = s;
  __syncthreads();
  for (int o = 1; o < SCAN_T; o <<= 1) {
    int v = (t >= o) ? part[t - o] : 0;
    __syncthreads();
    part[t] += v;
    __syncthreads();
  }
  int base = (t == 0) ? 0 : part[t - 1];
  for (int i = lo; i < hi; ++i) {
    off[i] = base; cursor[i] = base; base += deg[i];
  }
  if (t == SCAN_T - 1) off[NN] = part[SCAN_T - 1];
}

__global__ __launch_bounds__(256) void csr_fill_k(const int* __restrict__ dst,
                                                  int* __restrict__ cursor,
                                                  int* __restrict__ eids) {
  int e = blockIdx.x * 256 + threadIdx.x;
  if (e < NE) {
    int p = atomicAdd(&cursor[dst[e]], 1);
    eids[p] = e;
  }
}

// ---------------------------------------------------------------------------
// Projection writing bf16: out[n][0..127] (ushort) = node @ W (f32 in, bf16 w)
// W packed (c, c+64) in 32 KB LDS -> 5 blocks/CU. 2 rows per wave-iteration.
// Coalesced uint stores via shuffle-transpose: lane l stores cols (2l, 2l+1).
// ---------------------------------------------------------------------------
__global__ __launch_bounds__(256) void proj_bf16_k(
    const float* __restrict__ xin, const float* __restrict__ W,
    unsigned* __restrict__ outp) {
  __shared__ unsigned Wp[DIM * 64];   // 32 KB
  for (int t = threadIdx.x; t < DIM * 64; t += 256) {
    int i = t >> 6, c = t & 63;
    Wp[t] = bf16pk(W[i * DIM + c], W[i * DIM + c + 64]);
  }
  __syncthreads();
  int wid = threadIdx.x >> 6, l = threadIdx.x & 63;
  for (int n0 = (blockIdx.x * 4 + wid) * 2; n0 < NN; n0 += gridDim.x * 8) {
    int n1 = n0 + 1;                      // NN even
    const float* r0 = xin + (size_t)n0 * DIM;
    const float* r1 = xin + (size_t)n1 * DIM;
    float x0a = r0[l], x0b = r0[l + 64], x1a = r1[l], x1b = r1[l + 64];
    float a00 = 0, a01 = 0, a10 = 0, a11 = 0;
    #pragma unroll 16
    for (int i = 0; i < 64; ++i) {
      unsigned w = Wp[i * 64 + l];
      float s0 = __shfl(x0a, i, 64), s1 = __shfl(x1a, i, 64);
      float cl = bf_lo(w), ch = bf_hi(w);
      a00 = fmaf(s0, cl, a00); a01 = fmaf(s0, ch, a01);
      a10 = fmaf(s1, cl, a10); a11 = fmaf(s1, ch, a11);
    }
    #pragma unroll 16
    for (int i = 0; i < 64; ++i) {
      unsigned w = Wp[(64 + i) * 64 + l];
      float s0 = __shfl(x0b, i, 64), s1 = __shfl(x1b, i, 64);
      float cl = bf_lo(w), ch = bf_hi(w);
      a00 = fmaf(s0, cl, a00); a01 = fmaf(s0, ch, a01);
      a10 = fmaf(s1, cl, a10); a11 = fmaf(s1, ch, a11);
    }
    // lane l stores cols (2l, 2l+1): col 2l lives in lane (2l)&63, reg a00 if
    // 2l<64 else a01; col 2l+1 analogous.
    int i0 = (2 * l) & 63, i1 = (2 * l + 1) & 63;
    float e0a = __shfl(a00, i0, 64), e0b = __shfl(a01, i0, 64);
    float e1a = __shfl(a00, i1, 64), e1b = __shfl(a01, i1, 64);
    float c0 = (l < 32) ? e0a : e0b;
    float c1 = (l < 32) ? e1a : e1b;
    outp[(size_t)n0 * 64 + l] = bf16pk(c0, c1);
    float f0a = __shfl(a10, i0, 64), f0b = __shfl(a11, i0, 64);
    float f1a = __shfl(a10, i1, 64), f1b = __shfl(a11, i1, 64);
    float d0 = (l < 32) ? f0a : f0b;
    float d1 = (l < 32) ? f1a : f1b;
    outp[(size_t)n1 * 64 + l] = bf16pk(d0, d1);
  }
}

// ---------------------------------------------------------------------------
// Edge logits from bf16 q/k (halved gather bytes)
// ---------------------------------------------------------------------------
__global__ __launch_bounds__(256) void edge_logits_k(
    const unsigned* __restrict__ kb16, const unsigned* __restrict__ qb16,
    const float* __restrict__ ba, const int* __restrict__ src,
    const int* __restrict__ dst, const float* __restrict__ Wdis,
    float* __restrict__ elog) {
  int idx = blockIdx.x * 256 + threadIdx.x;
  if (idx >= NE * NH) return;
  int e = idx >> 3, h = idx & 7;
  int s = src[e], t = dst[e];
  const uint4* kp = (const uint4*)(kb16 + (size_t)s * 64 + h * 8);
  const uint4* qp = (const uint4*)(qb16 + (size_t)t * 64 + h * 8);
  uint4 A0 = kp[0], A1 = kp[1];
  uint4 B0 = qp[0], B1 = qp[1];
  float sc = 0.f;
  sc = fmaf(bf_lo(A0.x), bf_lo(B0.x), sc); sc = fmaf(bf_hi(A0.x), bf_hi(B0.x), sc);
  sc = fmaf(bf_lo(A0.y), bf_lo(B0.y), sc); sc = fmaf(bf_hi(A0.y), bf_hi(B0.y), sc);
  sc = fmaf(bf_lo(A0.z), bf_lo(B0.z), sc); sc = fmaf(bf_hi(A0.z), bf_hi(B0.z), sc);
  sc = fmaf(bf_lo(A0.w), bf_lo(B0.w), sc); sc = fmaf(bf_hi(A0.w), bf_hi(B0.w), sc);
  sc = fmaf(bf_lo(A1.x), bf_lo(B1.x), sc); sc = fmaf(bf_hi(A1.x), bf_hi(B1.x), sc);
  sc = fmaf(bf_lo(A1.y), bf_lo(B1.y), sc); sc = fmaf(bf_hi(A1.y), bf_hi(B1.y), sc);
  sc = fmaf(bf_lo(A1.z), bf_lo(B1.z), sc); sc = fmaf(bf_hi(A1.z), bf_hi(B1.z), sc);
  sc = fmaf(bf_lo(A1.w), bf_lo(B1.w), sc); sc = fmaf(bf_hi(A1.w), bf_hi(B1.w), sc);
  elog[idx] = sc * 0.25f + ba[e] * Wdis[h];
}

// ---------------------------------------------------------------------------
// Per-node: softmax (CSR) + weighted bond gather (4-deep pipeline) +
// Wv projection + beta gate + LN1. LDS exactly 40 KB -> 4 blocks/CU.
// ---------------------------------------------------------------------------
__global__ __launch_bounds__(256) void node_attn_k(
    const float* __restrict__ bond, const float* __restrict__ WvG,
    const float* __restrict__ elog, const int* __restrict__ off,
    const int* __restrict__ eids, const float* __restrict__ x,
    const float* __restrict__ Wb, const float* __restrict__ g1,
    const float* __restrict__ b1, float* __restrict__ he,
    float* __restrict__ hbuf) {
  __shared__ unsigned Wvpk[DIM * 64];      // 32 KB, packed cols (c, c+64)
  __shared__ unsigned gbuf[4][NH][64];     // 8 KB, bf16-packed g (cols 2i,2i+1)
  for (int t = threadIdx.x; t < DIM * 64; t += 256) {
    int i = t >> 6, c = t & 63;
    Wvpk[t] = bf16pk(WvG[i * DIM + c], WvG[i * DIM + c + 64]);
  }
  __syncthreads();
  const int wid = threadIdx.x >> 6, l = threadIdx.x & 63;
  const int hh = l & 7, slot = l >> 3;
  // beta/LN params in registers (lane-indexed, node-invariant)
  const float wb0 = Wb[l],          wb1 = Wb[l + 64];
  const float wb2 = Wb[DIM + l],    wb3 = Wb[DIM + l + 64];
  const float wb4 = Wb[2*DIM + l],  wb5 = Wb[2*DIM + l + 64];
  const float gl0 = g1[l], gl1 = g1[l + 64];
  const float bl0 = b1[l], bl1 = b1[l + 64];

  for (int n = blockIdx.x * 4 + wid; n < NN; n += gridDim.x * 4) {
    int o0 = off[n];
    int deg = off[n + 1] - o0;
    float acc[16];
    #pragma unroll
    for (int i = 0; i < 16; ++i) acc[i] = 0.f;
    if (deg > 0) {
      // pass 1: per-head max (lanes = 8 slots x 8 heads)
      float vmax = -1e30f;
      for (int j = slot; j < deg; j += 8)
        vmax = fmaxf(vmax, elog[eids[o0 + j] * NH + hh]);
      vmax = fmaxf(vmax, __shfl_xor(vmax, 8, 64));
      vmax = fmaxf(vmax, __shfl_xor(vmax, 16, 64));
      vmax = fmaxf(vmax, __shfl_xor(vmax, 32, 64));
      // pass 2: per-head denominator
      float den = 0.f;
      for (int j = slot; j < deg; j += 8)
        den += __expf(elog[eids[o0 + j] * NH + hh] - vmax);
      den += __shfl_xor(den, 8, 64);
      den += __shfl_xor(den, 16, 64);
      den += __shfl_xor(den, 32, 64);
      float rden = 1.f / (den + 1e-16f);
      // pass 3: 4-deep pipelined weighted gather of bond rows
      float2 bcur[4]; float lgcur[4];
      #pragma unroll
      for (int a = 0; a < 4; ++a) {
        int j = (a < deg) ? a : (deg - 1);
        int e = eids[o0 + j];
        bcur[a] = *(const float2*)(bond + (size_t)e * DIM + 2 * l);
        lgcur[a] = elog[e * NH + hh];
      }
      for (int jb = 0; jb < deg; jb += 4) {
        float2 bnext[4]; float lgnext[4];
        if (jb + 4 < deg) {
          #pragma unroll
          for (int a = 0; a < 4; ++a) {
            int j = jb + 4 + a; if (j >= deg) j = deg - 1;
            int e = eids[o0 + j];
            bnext[a] = *(const float2*)(bond + (size_t)e * DIM + 2 * l);
            lgnext[a] = elog[e * NH + hh];
          }
        } else {
          #pragma unroll
          for (int a = 0; a < 4; ++a) { bnext[a] = make_float2(0.f, 0.f); lgnext[a] = 0.f; }
        }
        #pragma unroll
        for (int a = 0; a < 4; ++a) {
          float am = ((jb + a) < deg) ? __expf(lgcur[a] - vmax) * rden : 0.f;
          #pragma unroll
          for (int h = 0; h < 8; ++h) {
            float ah = __shfl(am, h, 64);
            acc[2 * h]     = fmaf(ah, bcur[a].x, acc[2 * h]);
            acc[2 * h + 1] = fmaf(ah, bcur[a].y, acc[2 * h + 1]);
          }
        }
        #pragma unroll
        for (int a = 0; a < 4; ++a) { bcur[a] = bnext[a]; lgcur[a] = lgnext[a]; }
      }
    }
    // stash g (bf16-packed), wave-private -> no barrier
    #pragma unroll
    for (int h = 0; h < 8; ++h)
      gbuf[wid][h][l] = bf16pk(acc[2 * h], acc[2 * h + 1]);
    // projection: ft cols (l, l+64); heads h0 = l>>4, h1 = 4 + (l>>4)
    int h0 = l >> 4, h1 = 4 + (l >> 4);
    float f0 = 0.f, f1 = 0.f;
    #pragma unroll 8
    for (int ii = 0; ii < 64; ++ii) {
      unsigned u = gbuf[wid][h0][ii];
      unsigned v = gbuf[wid][h1][ii];
      unsigned w0 = Wvpk[(2 * ii) * 64 + l];
      unsigned w1 = Wvpk[(2 * ii + 1) * 64 + l];
      f0 = fmaf(bf_lo(u), bf_lo(w0), f0); f0 = fmaf(bf_hi(u), bf_lo(w1), f0);
      f1 = fmaf(bf_lo(v), bf_hi(w0), f1); f1 = fmaf(bf_hi(v), bf_hi(w1), f1);
    }
    // beta gate + LN1
    float x0 = x[(size_t)n * DIM + l], x1 = x[(size_t)n * DIM + l + 64];
    float s = f0 * wb0 + x0 * wb2 + (f0 - x0) * wb4
            + f1 * wb1 + x1 * wb3 + (f1 - x1) * wb5;
    s = wave_sum64(s);
    float beta = 1.f / (1.f + __expf(-s));
    float he0 = beta * x0 + (1.f - beta) * f0;
    float he1 = beta * x1 + (1.f - beta) * f1;
    he[(size_t)n * DIM + l] = he0;
    he[(size_t)n * DIM + l + 64] = he1;
    float mu = wave_sum64(he0 + he1) * (1.f / DIM);
    float vr = wave_sum64(he0 * he0 + he1 * he1) * (1.f / DIM) - mu * mu;
    float rs = rsqrtf(vr + 1e-5f);
    hbuf[(size_t)n * DIM + l]      = (he0 - mu) * rs * gl0 + bl0;
    hbuf[(size_t)n * DIM + l + 64] = (he1 - mu) * rs * gl1 + bl1;
  }
}

// ---------------------------------------------------------------------------
// FF1 col-half: hid[n, w_off + {l, l+64}] = relu(hbuf @ W1[:, w_off..]).
// 32 KB LDS -> 5 blocks/CU. Launched twice (w_off = 0, 128).
// ---------------------------------------------------------------------------
__global__ __launch_bounds__(256) void ff1_k(
    const float* __restrict__ xin, const float* __restrict__ W1,
    float* __restrict__ hid, int w_off) {
  __shared__ unsigned Wp[DIM * 64];   // 32 KB
  for (int t = threadIdx.x; t < DIM * 64; t += 256) {
    int i = t >> 6, c = t & 63;
    Wp[t] = bf16pk(W1[i * 256 + w_off + c], W1[i * 256 + w_off + c + 64]);
  }
  __syncthreads();
  int wid = threadIdx.x >> 6, l = threadIdx.x & 63;
  for (int n0 = (blockIdx.x * 4 + wid) * 2; n0 < NN; n0 += gridDim.x * 8) {
    int n1 = n0 + 1;
    const float* r0 = xin + (size_t)n0 * DIM;
    const float* r1 = xin + (size_t)n1 * DIM;
    float x0a = r0[l], x0b = r0[l + 64], x1a = r1[l], x1b = r1[l + 64];
    float a00 = 0, a01 = 0, a10 = 0, a11 = 0;
    #pragma unroll 16
    for (int i = 0; i < 64; ++i) {
      unsigned w = Wp[i * 64 + l];
      float s0 = __shfl(x0a, i, 64), s1 = __shfl(x1a, i, 64);
      float cl = bf_lo(w), ch = bf_hi(w);
      a00 = fmaf(s0, cl, a00); a01 = fmaf(s0, ch, a01);
      a10 = fmaf(s1, cl, a10); a11 = fmaf(s1, ch, a11);
    }
    #pragma unroll 16
    for (int i = 0; i < 64; ++i) {
      unsigned w = Wp[(64 + i) * 64 + l];
      float s0 = __shfl(x0b, i, 64), s1 = __shfl(x1b, i, 64);
      float cl = bf_lo(w), ch = bf_hi(w);
      a00 = fmaf(s0, cl, a00); a01 = fmaf(s0, ch, a01);
      a10 = fmaf(s1, cl, a10); a11 = fmaf(s1, ch, a11);
    }
    float* o0 = hid + (size_t)n0 * 256 + w_off;
    float* o1 = hid + (size_t)n1 * 256 + w_off;
    o0[l] = fmaxf(a00, 0.f); o0[l + 64] = fmaxf(a01, 0.f);
    o1[l] = fmaxf(a10, 0.f); o1[l + 64] = fmaxf(a11, 0.f);
  }
}

// ---------------------------------------------------------------------------
// FF2 + residual + final LN (g=1,b=0). W2 [256][128] packed (c, c+64) (64 KB)
// ---------------------------------------------------------------------------
__global__ __launch_bounds__(256) void ff2_k(
    const float* __restrict__ hid, const float* __restrict__ W2,
    const float* __restrict__ he, float* __restrict__ outp) {
  __shared__ unsigned Wp[256 * 64];  // 64 KB
  for (int t = threadIdx.x; t < 256 * 64; t += 256) {
    int i = t >> 6, c = t & 63;
    Wp[t] = bf16pk(W2[i * DIM + c], W2[i * DIM + c + 64]);
  }
  __syncthreads();
  int wid = threadIdx.x >> 6, l = threadIdx.x & 63;
  for (int n0 = (blockIdx.x * 4 + wid) * 2; n0 < NN; n0 += gridDim.x * 8) {
    int n1 = n0 + 1;
    const float* r0 = hid + (size_t)n0 * 256;
    const float* r1 = hid + (size_t)n1 * 256;
    float x0[4] = {r0[l], r0[l + 64], r0[l + 128], r0[l + 192]};
    float x1[4] = {r1[l], r1[l + 64], r1[l + 128], r1[l + 192]};
    float a00 = 0, a01 = 0, a10 = 0, a11 = 0;
    #pragma unroll
    for (int q = 0; q < 4; ++q) {
      #pragma unroll 16
      for (int i = 0; i < 64; ++i) {
        unsigned w = Wp[(q * 64 + i) * 64 + l];
        float s0 = __shfl(x0[q], i, 64), s1 = __shfl(x1[q], i, 64);
        float cl = bf_lo(w), ch = bf_hi(w);
        a00 = fmaf(s0, cl, a00); a01 = fmaf(s0, ch, a01);
        a10 = fmaf(s1, cl, a10); a11 = fmaf(s1, ch, a11);
      }
    }
    float z00 = a00 + he[(size_t)n0 * DIM + l];
    float z01 = a01 + he[(size_t)n0 * DIM + l + 64];
    float z10 = a10 + he[(size_t)n1 * DIM + l];
    float z11 = a11 + he[(size_t)n1 * DIM + l + 64];
    float mu0 = wave_sum64(z00 + z01) * (1.f / DIM);
    float vr0 = wave_sum64(z00 * z00 + z01 * z01) * (1.f / DIM) - mu0 * mu0;
    float rs0 = rsqrtf(vr0 + 1e-5f);
    float mu1 = wave_sum64(z10 + z11) * (1.f / DIM);
    float vr1 = wave_sum64(z10 * z10 + z11 * z11) * (1.f / DIM) - mu1 * mu1;
    float rs1 = rsqrtf(vr1 + 1e-5f);
    outp[(size_t)n0 * DIM + l]      = (z00 - mu0) * rs0;
    outp[(size_t)n0 * DIM + l + 64] = (z01 - mu0) * rs0;
    outp[(size_t)n1 * DIM + l]      = (z10 - mu1) * rs1;
    outp[(size_t)n1 * DIM + l + 64] = (z11 - mu1) * rs1;
  }
}

// ---------------------------------------------------------------------------
extern "C" void kernel_launch(void* const* d_in, const int* in_sizes, int n_in,
                              void* d_out, int out_size, void* d_ws, size_t ws_size,
                              hipStream_t stream) {
  const float* node = (const float*)d_in[0];
  const float* bond = (const float*)d_in[1];
  const float* ba   = (const float*)d_in[2];
  const int*   src  = (const int*)  d_in[3];
  const int*   dst  = (const int*)  d_in[4];
  const float* Wk   = (const float*)d_in[5];
  const float* Wq   = (const float*)d_in[6];
  const float* Wv   = (const float*)d_in[7];
  const float* Wdis = (const float*)d_in[8];
  const float* Wb   = (const float*)d_in[9];
  const float* g1   = (const float*)d_in[10];
  const float* b1   = (const float*)d_in[11];
  const float* W1   = (const float*)d_in[12];
  const float* W2   = (const float*)d_in[13];
  float* out = (float*)d_out;

  // workspace (floats):
  //  A [0, 6.4M):        qb16 (3.2M) + kb16 (3.2M)  -> later he (6.4M)
  //  B [6.4M, 11.52M):   elog (5.12M)
  //  C [11.52M, 17.92M): hbuf (6.4M)
  //  D [17.92M, 30.72M): hid (12.8M)
  //  E [30.72M, ..):     CSR ints
  float* ws = (float*)d_ws;
  unsigned* qb16 = (unsigned*)ws;                       // NN*64 uints
  unsigned* kb16 = (unsigned*)(ws + (size_t)3200000);
  float* he   = ws;
  float* elog = ws + (size_t)6400000;
  float* hbuf = ws + (size_t)11520000;
  float* hid  = ws + (size_t)17920000;
  int* deg    = (int*)(ws + (size_t)30720000);
  int* off    = deg + (NN + 1);
  int* cursor = off + (NN + 1);
  int* eids   = cursor + (NN + 1);

  hipMemsetAsync(deg, 0, (size_t)(NN + 1) * 4, stream);

  // CSR build
  csr_count_k<<<(NE + 255) / 256, 256, 0, stream>>>(dst, deg);
  scan_k<<<1, 1024, 0, stream>>>(deg, off, cursor);
  csr_fill_k<<<(NE + 255) / 256, 256, 0, stream>>>(dst, cursor, eids);

  // q/k projections -> bf16
  proj_bf16_k<<<1280, 256, 0, stream>>>(node, Wq, qb16);
  proj_bf16_k<<<1280, 256, 0, stream>>>(node, Wk, kb16);

  // edge logits
  edge_logits_k<<<(NE * NH + 255) / 256, 256, 0, stream>>>(
      kb16, qb16, ba, src, dst, Wdis, elog);

  // per-node attention + gate + LN1
  node_attn_k<<<1024, 256, 0, stream>>>(bond, Wv, elog, off, eids, node,
                                        Wb, g1, b1, he, hbuf);

  // FFN
  ff1_k<<<1024, 256, 0, stream>>>(hbuf, W1, hid, 0);
  ff1_k<<<1024, 256, 0, stream>>>(hbuf, W1, hid, 128);
  ff2_k<<<512, 256, 0, stream>>>(hid, W2, he, out);
}

// Round 4
// 1051.526 us; speedup vs baseline: 1.3524x; 1.3524x over previous
//
#include <hip/hip_runtime.h>
#include <math.h>

#define NN 50000
#define NE 640000
#define DIM 128
#define NH 8

typedef unsigned short u16;
typedef __attribute__((ext_vector_type(8))) short short8;
typedef __attribute__((ext_vector_type(4))) float f32x4;

__device__ __forceinline__ float wave_sum64(float v) {
  #pragma unroll
  for (int m = 32; m >= 1; m >>= 1) v += __shfl_xor(v, m, 64);
  return v;
}
__device__ __forceinline__ unsigned bf16pk(float a, float b) {
  unsigned ua = __float_as_uint(a); ua = (ua + 0x7fffu + ((ua >> 16) & 1u)) >> 16;
  unsigned ub = __float_as_uint(b); ub = (ub + 0x7fffu + ((ub >> 16) & 1u)) & 0xffff0000u;
  return ua | ub;
}
__device__ __forceinline__ u16 bf16c(float x) {
  unsigned u = __float_as_uint(x);
  return (u16)((u + 0x7fffu + ((u >> 16) & 1u)) >> 16);
}
__device__ __forceinline__ float bf_lo(unsigned v) { return __uint_as_float(v << 16); }
__device__ __forceinline__ float bf_hi(unsigned v) { return __uint_as_float(v & 0xffff0000u); }

#define AS1(p) ((const __attribute__((address_space(1))) unsigned*)(p))
#define AS3(p) ((__attribute__((address_space(3))) unsigned*)(p))

// ---------------------------------------------------------------------------
// CSR build
// ---------------------------------------------------------------------------
__global__ __launch_bounds__(256) void csr_count_k(const int* __restrict__ dst,
                                                   int* __restrict__ deg) {
  int e = blockIdx.x * 256 + threadIdx.x;
  if (e < NE) atomicAdd(&deg[dst[e]], 1);
}

#define SCAN_T 1024
#define SCHUNK 49
__global__ __launch_bounds__(1024) void scan_k(const int* __restrict__ deg,
                                               int* __restrict__ off,
                                               int* __restrict__ cursor) {
  __shared__ int part[SCAN_T];
  int t = threadIdx.x;
  int lo = t * SCHUNK, hi = lo + SCHUNK; if (hi > NN) hi = NN;
  int s = 0;
  for (int i = lo; i < hi; ++i) s += deg[i];
  part[t] = s;
  __syncthreads();
  for (int o = 1; o < SCAN_T; o <<= 1) {
    int v = (t >= o) ? part[t - o] : 0;
    __syncthreads();
    part[t] += v;
    __syncthreads();
  }
  int base = (t == 0) ? 0 : part[t - 1];
  for (int i = lo; i < hi; ++i) {
    off[i] = base; cursor[i] = base; base += deg[i];
  }
  if (t == SCAN_T - 1) off[NN] = part[SCAN_T - 1];
}

__global__ __launch_bounds__(256) void csr_fill_k(const int* __restrict__ dst,
                                                  int* __restrict__ cursor,
                                                  int* __restrict__ eids) {
  int e = blockIdx.x * 256 + threadIdx.x;
  if (e < NE) {
    int p = atomicAdd(&cursor[dst[e]], 1);
    eids[p] = e;
  }
}

// ---------------------------------------------------------------------------
// f32 -> bf16 conversion (node_emb): each thread packs 2 floats into 1 uint
// ---------------------------------------------------------------------------
__global__ __launch_bounds__(256) void cvt_node_k(const float* __restrict__ x,
                                                  unsigned* __restrict__ o) {
  int t = blockIdx.x * 256 + threadIdx.x;
  if (t < NN * 64) {
    float2 v = *(const float2*)(x + (size_t)2 * t);
    o[t] = bf16pk(v.x, v.y);
  }
}

// ---------------------------------------------------------------------------
// Weight prep: Wt[n][k] (bf16, k-contiguous) = W[k][n] (f32 row-major)
// ---------------------------------------------------------------------------
__global__ __launch_bounds__(256) void wprep_k(const float* __restrict__ W,
                                               u16* __restrict__ Wt,
                                               int K, int N) {
  int t = blockIdx.x * 256 + threadIdx.x;
  if (t < K * N) {
    int n = t / K, k = t - n * K;
    Wt[t] = bf16c(W[(size_t)k * N + n]);
  }
}

// ---------------------------------------------------------------------------
// MFMA GEMM: qb16/kb16 = node16 @ Wq / Wk  (M=NN, K=128, N=128+128)
// Block = 4 waves; waves 0,1 -> Wq cols 0-63/64-127; waves 2,3 -> Wk.
// A-tile 64x128 bf16 staged via global_load_lds (16 KB).
// ---------------------------------------------------------------------------
__global__ __launch_bounds__(256) void qk_mfma_k(
    const u16* __restrict__ A, const u16* __restrict__ Wtq,
    const u16* __restrict__ Wtk, u16* __restrict__ qo,
    u16* __restrict__ ko) {
  __shared__ u16 At[64 * 128];  // 16 KB
  const int wid = threadIdx.x >> 6, l = threadIdx.x & 63;
  const int quad = l >> 4, l16 = l & 15;
  const int c0 = (wid & 1) * 64;
  const u16* wt = (wid < 2) ? Wtq : Wtk;
  u16* ob = (wid < 2) ? qo : ko;
  short8 bfr[4][4];
  #pragma unroll
  for (int ct = 0; ct < 4; ++ct)
    #pragma unroll
    for (int ks = 0; ks < 4; ++ks)
      bfr[ct][ks] = *(const short8*)(wt + (c0 + ct * 16 + l16) * 128 + ks * 32 + quad * 8);
  const int ntiles = (NN + 63) / 64;
  for (int t = blockIdx.x; t < ntiles; t += gridDim.x) {
    const char* gsrc = (const char*)A + (size_t)t * 64 * 128 * 2;
    #pragma unroll
    for (int i = 0; i < 4; ++i) {
      int off = wid * 4096 + i * 1024;
      __builtin_amdgcn_global_load_lds(AS1(gsrc + off + l * 16),
                                       AS3((char*)At + off), 16, 0, 0);
    }
    __syncthreads();
    f32x4 acc[4][4];
    #pragma unroll
    for (int rt = 0; rt < 4; ++rt)
      #pragma unroll
      for (int ct = 0; ct < 4; ++ct)
        acc[rt][ct] = (f32x4){0.f, 0.f, 0.f, 0.f};
    #pragma unroll
    for (int ks = 0; ks < 4; ++ks) {
      short8 af[4];
      #pragma unroll
      for (int rt = 0; rt < 4; ++rt)
        af[rt] = *(const short8*)(At + (rt * 16 + l16) * 128 + ks * 32 + quad * 8);
      #pragma unroll
      for (int rt = 0; rt < 4; ++rt)
        #pragma unroll
        for (int ct = 0; ct < 4; ++ct)
          acc[rt][ct] = __builtin_amdgcn_mfma_f32_16x16x32_bf16(
              af[rt], bfr[ct][ks], acc[rt][ct], 0, 0, 0);
    }
    __syncthreads();
    #pragma unroll
    for (int rt = 0; rt < 4; ++rt)
      #pragma unroll
      for (int r = 0; r < 4; ++r) {
        int row = t * 64 + rt * 16 + quad * 4 + r;
        if (row < NN) {
          u16* op = ob + (size_t)row * 128 + c0 + l16;
          #pragma unroll
          for (int ct = 0; ct < 4; ++ct) op[ct * 16] = bf16c(acc[rt][ct][r]);
        }
      }
  }
}

// ---------------------------------------------------------------------------
// MFMA GEMM: hid16 = relu(hbuf16 @ W1)  (K=128, N=256)
// ---------------------------------------------------------------------------
__global__ __launch_bounds__(256) void ff1_mfma_k(
    const u16* __restrict__ A, const u16* __restrict__ Wt,
    u16* __restrict__ O) {
  __shared__ u16 At[64 * 128];  // 16 KB
  const int wid = threadIdx.x >> 6, l = threadIdx.x & 63;
  const int quad = l >> 4, l16 = l & 15;
  const int c0 = wid * 64;
  short8 bfr[4][4];
  #pragma unroll
  for (int ct = 0; ct < 4; ++ct)
    #pragma unroll
    for (int ks = 0; ks < 4; ++ks)
      bfr[ct][ks] = *(const short8*)(Wt + (c0 + ct * 16 + l16) * 128 + ks * 32 + quad * 8);
  const int ntiles = (NN + 63) / 64;
  for (int t = blockIdx.x; t < ntiles; t += gridDim.x) {
    const char* gsrc = (const char*)A + (size_t)t * 64 * 128 * 2;
    #pragma unroll
    for (int i = 0; i < 4; ++i) {
      int off = wid * 4096 + i * 1024;
      __builtin_amdgcn_global_load_lds(AS1(gsrc + off + l * 16),
                                       AS3((char*)At + off), 16, 0, 0);
    }
    __syncthreads();
    f32x4 acc[4][4];
    #pragma unroll
    for (int rt = 0; rt < 4; ++rt)
      #pragma unroll
      for (int ct = 0; ct < 4; ++ct)
        acc[rt][ct] = (f32x4){0.f, 0.f, 0.f, 0.f};
    #pragma unroll
    for (int ks = 0; ks < 4; ++ks) {
      short8 af[4];
      #pragma unroll
      for (int rt = 0; rt < 4; ++rt)
        af[rt] = *(const short8*)(At + (rt * 16 + l16) * 128 + ks * 32 + quad * 8);
      #pragma unroll
      for (int rt = 0; rt < 4; ++rt)
        #pragma unroll
        for (int ct = 0; ct < 4; ++ct)
          acc[rt][ct] = __builtin_amdgcn_mfma_f32_16x16x32_bf16(
              af[rt], bfr[ct][ks], acc[rt][ct], 0, 0, 0);
    }
    __syncthreads();
    #pragma unroll
    for (int rt = 0; rt < 4; ++rt)
      #pragma unroll
      for (int r = 0; r < 4; ++r) {
        int row = t * 64 + rt * 16 + quad * 4 + r;
        if (row < NN) {
          u16* op = O + (size_t)row * 256 + c0 + l16;
          #pragma unroll
          for (int ct = 0; ct < 4; ++ct)
            op[ct * 16] = bf16c(fmaxf(acc[rt][ct][r], 0.f));
        }
      }
  }
}

// ---------------------------------------------------------------------------
// MFMA GEMM: z = hid16 @ W2 + he  (K=256, N=128), z f32
// ---------------------------------------------------------------------------
__global__ __launch_bounds__(256) void ff2_mfma_k(
    const u16* __restrict__ A, const u16* __restrict__ Wt,
    const float* __restrict__ he, float* __restrict__ Z) {
  __shared__ u16 At[64 * 256];  // 32 KB
  const int wid = threadIdx.x >> 6, l = threadIdx.x & 63;
  const int quad = l >> 4, l16 = l & 15;
  const int c0 = wid * 32;
  short8 bfr[2][8];
  #pragma unroll
  for (int ct = 0; ct < 2; ++ct)
    #pragma unroll
    for (int ks = 0; ks < 8; ++ks)
      bfr[ct][ks] = *(const short8*)(Wt + (c0 + ct * 16 + l16) * 256 + ks * 32 + quad * 8);
  const int ntiles = (NN + 63) / 64;
  for (int t = blockIdx.x; t < ntiles; t += gridDim.x) {
    const char* gsrc = (const char*)A + (size_t)t * 64 * 256 * 2;
    #pragma unroll
    for (int i = 0; i < 8; ++i) {
      int off = wid * 8192 + i * 1024;
      __builtin_amdgcn_global_load_lds(AS1(gsrc + off + l * 16),
                                       AS3((char*)At + off), 16, 0, 0);
    }
    __syncthreads();
    f32x4 acc[4][2];
    #pragma unroll
    for (int rt = 0; rt < 4; ++rt)
      #pragma unroll
      for (int ct = 0; ct < 2; ++ct)
        acc[rt][ct] = (f32x4){0.f, 0.f, 0.f, 0.f};
    #pragma unroll
    for (int ks = 0; ks < 8; ++ks) {
      short8 af[4];
      #pragma unroll
      for (int rt = 0; rt < 4; ++rt)
        af[rt] = *(const short8*)(At + (rt * 16 + l16) * 256 + ks * 32 + quad * 8);
      #pragma unroll
      for (int rt = 0; rt < 4; ++rt)
        #pragma unroll
        for (int ct = 0; ct < 2; ++ct)
          acc[rt][ct] = __builtin_amdgcn_mfma_f32_16x16x32_bf16(
              af[rt], bfr[ct][ks], acc[rt][ct], 0, 0, 0);
    }
    __syncthreads();
    #pragma unroll
    for (int rt = 0; rt < 4; ++rt)
      #pragma unroll
      for (int r = 0; r < 4; ++r) {
        int row = t * 64 + rt * 16 + quad * 4 + r;
        if (row < NN) {
          #pragma unroll
          for (int ct = 0; ct < 2; ++ct) {
            size_t idx = (size_t)row * 128 + c0 + ct * 16 + l16;
            Z[idx] = acc[rt][ct][r] + he[idx];
          }
        }
      }
  }
}

// ---------------------------------------------------------------------------
// Edge logits: elog[e,h] = dot(k[src],q[dst])_h / 4 + ba*Wdis (bf16 q/k)
// ---------------------------------------------------------------------------
__global__ __launch_bounds__(256) void edge_logits_k(
    const unsigned* __restrict__ kb16, const unsigned* __restrict__ qb16,
    const float* __restrict__ ba, const int* __restrict__ src,
    const int* __restrict__ dst, const float* __restrict__ Wdis,
    float* __restrict__ elog) {
  int idx = blockIdx.x * 256 + threadIdx.x;
  if (idx >= NE * NH) return;
  int e = idx >> 3, h = idx & 7;
  int s = src[e], t = dst[e];
  const uint4* kp = (const uint4*)(kb16 + (size_t)s * 64 + h * 8);
  const uint4* qp = (const uint4*)(qb16 + (size_t)t * 64 + h * 8);
  uint4 A0 = kp[0], A1 = kp[1];
  uint4 B0 = qp[0], B1 = qp[1];
  float sc = 0.f;
  sc = fmaf(bf_lo(A0.x), bf_lo(B0.x), sc); sc = fmaf(bf_hi(A0.x), bf_hi(B0.x), sc);
  sc = fmaf(bf_lo(A0.y), bf_lo(B0.y), sc); sc = fmaf(bf_hi(A0.y), bf_hi(B0.y), sc);
  sc = fmaf(bf_lo(A0.z), bf_lo(B0.z), sc); sc = fmaf(bf_hi(A0.z), bf_hi(B0.z), sc);
  sc = fmaf(bf_lo(A0.w), bf_lo(B0.w), sc); sc = fmaf(bf_hi(A0.w), bf_hi(B0.w), sc);
  sc = fmaf(bf_lo(A1.x), bf_lo(B1.x), sc); sc = fmaf(bf_hi(A1.x), bf_hi(B1.x), sc);
  sc = fmaf(bf_lo(A1.y), bf_lo(B1.y), sc); sc = fmaf(bf_hi(A1.y), bf_hi(B1.y), sc);
  sc = fmaf(bf_lo(A1.z), bf_lo(B1.z), sc); sc = fmaf(bf_hi(A1.z), bf_hi(B1.z), sc);
  sc = fmaf(bf_lo(A1.w), bf_lo(B1.w), sc); sc = fmaf(bf_hi(A1.w), bf_hi(B1.w), sc);
  elog[idx] = sc * 0.25f + ba[e] * Wdis[h];
}

// ---------------------------------------------------------------------------
// Per-node SINGLE-PASS: unnormalized weighted bond gather + den, scale,
// Wv projection (LDS, conflict-free), beta gate + LN1.
// No max-subtraction (logits bounded ~|3|); softmax value identical.
// ---------------------------------------------------------------------------
__global__ __launch_bounds__(256) void node_attn_k(
    const float* __restrict__ bond, const float* __restrict__ WvG,
    const float* __restrict__ elog, const int* __restrict__ off,
    const int* __restrict__ eids, const float* __restrict__ x,
    const float* __restrict__ Wb, const float* __restrict__ g1,
    const float* __restrict__ b1, float* __restrict__ he,
    unsigned* __restrict__ hbuf16) {
  __shared__ unsigned Wvpk[DIM * 64];       // 32 KB, packed cols (c, c+64)
  __shared__ unsigned gbuf[4][NH][67];      // bf16-packed g, pad 67 (no conflicts)
  for (int t = threadIdx.x; t < DIM * 64; t += 256) {
    int i = t >> 6, c = t & 63;
    Wvpk[t] = bf16pk(WvG[i * DIM + c], WvG[i * DIM + c + 64]);
  }
  __syncthreads();
  const int wid = threadIdx.x >> 6, l = threadIdx.x & 63;
  const int hh = l & 7;
  const float wb0 = Wb[l],         wb1 = Wb[l + 64];
  const float wb2 = Wb[DIM + l],   wb3 = Wb[DIM + l + 64];
  const float wb4 = Wb[2*DIM + l], wb5 = Wb[2*DIM + l + 64];
  const float gl0 = g1[l], gl1 = g1[l + 64];
  const float bl0 = b1[l], bl1 = b1[l + 64];

  for (int n = blockIdx.x * 4 + wid; n < NN; n += gridDim.x * 4) {
    int o0 = off[n];
    int deg = off[n + 1] - o0;
    float acc[16];
    #pragma unroll
    for (int i = 0; i < 16; ++i) acc[i] = 0.f;
    float dsum = 0.f;
    if (deg > 0) {
      float2 bcur[8]; float lgcur[8];
      #pragma unroll
      for (int a = 0; a < 8; ++a) {
        int j = (a < deg) ? a : (deg - 1);
        int e = eids[o0 + j];
        bcur[a] = *(const float2*)(bond + (size_t)e * DIM + 2 * l);
        lgcur[a] = elog[e * NH + hh];
      }
      for (int j = 0; j < deg; ++j) {
        int s = j & 7;
        float ex = __expf(lgcur[s]);
        float2 bv = bcur[s];
        int jn = j + 8;
        if (jn < deg) {
          int e = eids[o0 + jn];
          bcur[s] = *(const float2*)(bond + (size_t)e * DIM + 2 * l);
          lgcur[s] = elog[e * NH + hh];
        }
        dsum += ex;
        #pragma unroll
        for (int h = 0; h < 8; ++h) {
          float ah = __shfl(ex, h, 64);
          acc[2 * h]     = fmaf(ah, bv.x, acc[2 * h]);
          acc[2 * h + 1] = fmaf(ah, bv.y, acc[2 * h + 1]);
        }
      }
    }
    float rden = 1.f / (dsum + 1e-16f);      // per head hh (8 replicas)
    #pragma unroll
    for (int h = 0; h < 8; ++h) {
      float rh = __shfl(rden, h, 64);
      acc[2 * h] *= rh; acc[2 * h + 1] *= rh;
    }
    // stash g (bf16-packed, padded), wave-private -> no barrier
    #pragma unroll
    for (int h = 0; h < 8; ++h)
      gbuf[wid][h][l] = bf16pk(acc[2 * h], acc[2 * h + 1]);
    // projection: ft cols (l, l+64); heads h0 = l>>4, h1 = 4 + (l>>4)
    int h0 = l >> 4, h1 = 4 + (l >> 4);
    float f0 = 0.f, f1 = 0.f;
    #pragma unroll 8
    for (int ii = 0; ii < 64; ++ii) {
      unsigned u = gbuf[wid][h0][ii];
      unsigned v = gbuf[wid][h1][ii];
      unsigned w0 = Wvpk[(2 * ii) * 64 + l];
      unsigned w1 = Wvpk[(2 * ii + 1) * 64 + l];
      f0 = fmaf(bf_lo(u), bf_lo(w0), f0); f0 = fmaf(bf_hi(u), bf_lo(w1), f0);
      f1 = fmaf(bf_lo(v), bf_hi(w0), f1); f1 = fmaf(bf_hi(v), bf_hi(w1), f1);
    }
    // beta gate + LN1
    float x0 = x[(size_t)n * DIM + l], x1 = x[(size_t)n * DIM + l + 64];
    float s = f0 * wb0 + x0 * wb2 + (f0 - x0) * wb4
            + f1 * wb1 + x1 * wb3 + (f1 - x1) * wb5;
    s = wave_sum64(s);
    float beta = 1.f / (1.f + __expf(-s));
    float he0 = beta * x0 + (1.f - beta) * f0;
    float he1 = beta * x1 + (1.f - beta) * f1;
    he[(size_t)n * DIM + l] = he0;
    he[(size_t)n * DIM + l + 64] = he1;
    float mu = wave_sum64(he0 + he1) * (1.f / DIM);
    float vr = wave_sum64(he0 * he0 + he1 * he1) * (1.f / DIM) - mu * mu;
    float rs = rsqrtf(vr + 1e-5f);
    float v0 = (he0 - mu) * rs * gl0 + bl0;
    float v1 = (he1 - mu) * rs * gl1 + bl1;
    // shuffle-transpose to packed bf16 row layout: uint l holds cols (2l,2l+1)
    int i0 = (2 * l) & 63, i1 = (2 * l + 1) & 63;
    float a0 = __shfl(v0, i0, 64), b0 = __shfl(v1, i0, 64);
    float a1 = __shfl(v0, i1, 64), b1v = __shfl(v1, i1, 64);
    float c0 = (l < 32) ? a0 : b0;
    float c1 = (l < 32) ? a1 : b1v;
    hbuf16[(size_t)n * 64 + l] = bf16pk(c0, c1);
  }
}

// ---------------------------------------------------------------------------
// Final LN (g=1, b=0): out = LN(z)
// ---------------------------------------------------------------------------
__global__ __launch_bounds__(256) void ln_out_k(const float* __restrict__ z,
                                                float* __restrict__ outp) {
  const int wid = threadIdx.x >> 6, l = threadIdx.x & 63;
  int n = blockIdx.x * 4 + wid;
  if (n >= NN) return;
  float z0 = z[(size_t)n * DIM + l];
  float z1 = z[(size_t)n * DIM + l + 64];
  float mu = wave_sum64(z0 + z1) * (1.f / DIM);
  float vr = wave_sum64(z0 * z0 + z1 * z1) * (1.f / DIM) - mu * mu;
  float rs = rsqrtf(vr + 1e-5f);
  outp[(size_t)n * DIM + l]      = (z0 - mu) * rs;
  outp[(size_t)n * DIM + l + 64] = (z1 - mu) * rs;
}

// ---------------------------------------------------------------------------
extern "C" void kernel_launch(void* const* d_in, const int* in_sizes, int n_in,
                              void* d_out, int out_size, void* d_ws, size_t ws_size,
                              hipStream_t stream) {
  const float* node = (const float*)d_in[0];
  const float* bond = (const float*)d_in[1];
  const float* ba   = (const float*)d_in[2];
  const int*   src  = (const int*)  d_in[3];
  const int*   dst  = (const int*)  d_in[4];
  const float* Wk   = (const float*)d_in[5];
  const float* Wq   = (const float*)d_in[6];
  const float* Wv   = (const float*)d_in[7];
  const float* Wdis = (const float*)d_in[8];
  const float* Wb   = (const float*)d_in[9];
  const float* g1   = (const float*)d_in[10];
  const float* b1   = (const float*)d_in[11];
  const float* W1   = (const float*)d_in[12];
  const float* W2   = (const float*)d_in[13];
  float* out = (float*)d_out;

  // workspace byte layout (lifetimes disjoint where overlapped):
  //  R1 [0, 26.0M):   node16 [0,12.82M) + qb16 [13.0M,25.8M)  -> hid16 [0,25.64M)
  //  R2 [26M, 39M):   kb16 -> hbuf16 (padded)
  //  R3 [39M, 64.6M): elog (20.48M) -> z (25.6M)
  //  R4 [64.6M, 90.2M): he
  //  R5 [90.2M, 90.4M): Wtq/Wtk/Wt1/Wt2 (bf16 transposed weights)
  //  R6 [90.4M, ..):  CSR ints
  char* W = (char*)d_ws;
  u16* node16 = (u16*)(W);
  u16* qb16   = (u16*)(W + 13000000);
  u16* hid16  = (u16*)(W);
  u16* kb16   = (u16*)(W + 26000000);
  u16* hbuf16 = (u16*)(W + 26000000);
  float* elog = (float*)(W + 39000000);
  float* z    = (float*)(W + 39000000);
  float* he   = (float*)(W + 64600000);
  u16* Wtq    = (u16*)(W + 90200000);
  u16* Wtk    = Wtq + 128 * 128;
  u16* Wt1    = Wtk + 128 * 128;
  u16* Wt2    = Wt1 + 256 * 128;
  int* deg    = (int*)(W + 90400000);
  int* off    = deg + (NN + 1);
  int* cursor = off + (NN + 1);
  int* eids   = cursor + (NN + 1);

  hipMemsetAsync(deg, 0, (size_t)(NN + 1) * 4, stream);

  // CSR build
  csr_count_k<<<(NE + 255) / 256, 256, 0, stream>>>(dst, deg);
  scan_k<<<1, 1024, 0, stream>>>(deg, off, cursor);
  csr_fill_k<<<(NE + 255) / 256, 256, 0, stream>>>(dst, cursor, eids);

  // conversions / weight prep
  cvt_node_k<<<(NN * 64 + 255) / 256, 256, 0, stream>>>(node, (unsigned*)node16);
  wprep_k<<<(128 * 128 + 255) / 256, 256, 0, stream>>>(Wq, Wtq, 128, 128);
  wprep_k<<<(128 * 128 + 255) / 256, 256, 0, stream>>>(Wk, Wtk, 128, 128);
  wprep_k<<<(256 * 128 + 255) / 256, 256, 0, stream>>>(W1, Wt1, 128, 256);
  wprep_k<<<(256 * 128 + 255) / 256, 256, 0, stream>>>(W2, Wt2, 256, 128);

  const int ntiles = (NN + 63) / 64;  // 782

  // q/k projection (MFMA)
  qk_mfma_k<<<ntiles, 256, 0, stream>>>(node16, Wtq, Wtk, qb16, kb16);

  // edge logits
  edge_logits_k<<<(NE * NH + 255) / 256, 256, 0, stream>>>(
      (const unsigned*)kb16, (const unsigned*)qb16, ba, src, dst, Wdis, elog);

  // per-node attention + gate + LN1 (single gather pass)
  node_attn_k<<<4096, 256, 0, stream>>>(bond, Wv, elog, off, eids, node,
                                        Wb, g1, b1, he, (unsigned*)hbuf16);

  // FFN (MFMA) + residual, then final LN
  ff1_mfma_k<<<ntiles, 256, 0, stream>>>(hbuf16, Wt1, hid16);
  ff2_mfma_k<<<ntiles, 256, 0, stream>>>(hid16, Wt2, he, z);
  ln_out_k<<<(NN + 3) / 4, 256, 0, stream>>>(z, out);
}